// Round 4
// baseline (418.903 us; speedup 1.0000x reference)
//
#include <hip/hip_runtime.h>
#include <stdint.h>

// ============================================================================
// R4: fused QKV GEMM (plateau ~820 TF, kept) + 128-q-row MFMA flash attention
//     + single fused cast kernel + split-K=2 atomic Wo GEMM (+memset node).
// Shapes fixed: B=2, S=2048, D=2048, H=16, HD=128, window=512 (runtime-read).
// ws layout (bytes): xb@0 (16M, vtb aliases after QKV gemm) | wqkv@16M (25.2M)
//   wob@41.9M | qb@48M kb@64M vb@80M (16M apart = 8388608 elems) | ab@96M.
// ============================================================================

typedef __attribute__((ext_vector_type(8))) short short8;
typedef __attribute__((ext_vector_type(4))) float f32x4;

#define DEV static __device__ __forceinline__

DEV unsigned short f2bf(float f) {
  unsigned u = __builtin_bit_cast(unsigned, f);
  u += 0x7fffu + ((u >> 16) & 1u);  // RNE
  return (unsigned short)(u >> 16);
}

// async global->LDS, 16B/lane; LDS dest = wave-uniform base + lane*16
DEV void async16(const void* g, void* l) {
  __builtin_amdgcn_global_load_lds(
      (const __attribute__((address_space(1))) unsigned int*)g,
      (__attribute__((address_space(3))) unsigned int*)l, 16, 0, 0);
}

// ---------------------------------------------------------------------------
// Fused fp32 -> bf16 cast for x + Wq + Wk + Wv + Wo. 8 elems/thread.
// Block ranges: [0,4096) x | [4096,6144) Wq | [6144,8192) Wk |
//               [8192,10240) Wv | [10240,12288) Wo
// ---------------------------------------------------------------------------
__global__ __launch_bounds__(256) void cast_all(
    const float* __restrict__ x, const float* __restrict__ Wq,
    const float* __restrict__ Wk, const float* __restrict__ Wv,
    const float* __restrict__ Wo, unsigned short* __restrict__ xb,
    unsigned short* __restrict__ wqkv, unsigned short* __restrict__ wob) {
  const int bid = blockIdx.x;
  const float* src;
  unsigned short* dst;
  int i;
  if (bid < 4096) {
    src = x; dst = xb; i = bid * 256 + threadIdx.x;
  } else if (bid < 6144) {
    src = Wq; dst = wqkv; i = (bid - 4096) * 256 + threadIdx.x;
  } else if (bid < 8192) {
    src = Wk; dst = wqkv + 4194304; i = (bid - 6144) * 256 + threadIdx.x;
  } else if (bid < 10240) {
    src = Wv; dst = wqkv + 8388608; i = (bid - 8192) * 256 + threadIdx.x;
  } else {
    src = Wo; dst = wob; i = (bid - 10240) * 256 + threadIdx.x;
  }
  const float4* s4 = (const float4*)src;
  float4 a = s4[2 * (size_t)i], b = s4[2 * (size_t)i + 1];
  short8 o;
  o[0] = (short)f2bf(a.x); o[1] = (short)f2bf(a.y);
  o[2] = (short)f2bf(a.z); o[3] = (short)f2bf(a.w);
  o[4] = (short)f2bf(b.x); o[5] = (short)f2bf(b.y);
  o[6] = (short)f2bf(b.z); o[7] = (short)f2bf(b.w);
  *(short8*)(dst + 8 * (size_t)i) = o;
}

// ---------------------------------------------------------------------------
// C = A[M,K] * B[NT,K]^T, k-contiguous bf16. M=4096, K=2048.
// grid.y*128 = global col; nb = col>>11 selects output buffer (stride
// obuf_stride elems); local col = col & 2047, row stride 2048.
// ---------------------------------------------------------------------------
constexpr int GK = 2048, GN = 2048;

__global__ __launch_bounds__(256) void gemm_bt(
    const unsigned short* __restrict__ A, const unsigned short* __restrict__ B,
    unsigned short* __restrict__ Cout, size_t obuf_stride) {
  __shared__ short As[128 * 32];
  __shared__ short Bs[128 * 32];
  const int t = threadIdx.x;
  const int wave = t >> 6, lane = t & 63;
  const int row0 = blockIdx.x * 128;
  const int col0g = blockIdx.y * 128;            // global col in [0, N_total)
  const int nb = col0g >> 11, col0 = col0g & 2047;
  const int wrow = (wave >> 1) * 64, wcol = (wave & 1) * 64;

  f32x4 acc[4][4] = {};

  const int srow = wave * 16 + (lane >> 2);
  const int cg = (lane & 3) ^ (lane >> 4);
  const unsigned short* Ag0 = A + (size_t)(row0 + srow) * GK + cg * 8;
  const unsigned short* Ag1 = A + (size_t)(row0 + 64 + srow) * GK + cg * 8;
  const unsigned short* Bg0 = B + (size_t)(col0g + srow) * GK + cg * 8;
  const unsigned short* Bg1 = B + (size_t)(col0g + 64 + srow) * GK + cg * 8;
  char* lA0 = (char*)As + wave * 1024;
  char* lA1 = (char*)As + 4096 + wave * 1024;
  char* lB0 = (char*)Bs + wave * 1024;
  char* lB1 = (char*)Bs + 4096 + wave * 1024;

  const int quad = lane >> 4, l15 = lane & 15;
  const int cpos = quad ^ ((l15 >> 2) & 3);
  const short* ap[4];
  const short* bp[4];
#pragma unroll
  for (int i = 0; i < 4; ++i) {
    ap[i] = As + (wrow + i * 16 + l15) * 32 + cpos * 8;
    bp[i] = Bs + (wcol + i * 16 + l15) * 32 + cpos * 8;
  }

  for (int kk = 0; kk < GK; kk += 32) {
    async16(Ag0 + kk, lA0);
    async16(Ag1 + kk, lA1);
    async16(Bg0 + kk, lB0);
    async16(Bg1 + kk, lB1);
    __syncthreads();
    short8 af[4], bf[4];
#pragma unroll
    for (int i = 0; i < 4; ++i) af[i] = *(const short8*)ap[i];
#pragma unroll
    for (int i = 0; i < 4; ++i) bf[i] = *(const short8*)bp[i];
#pragma unroll
    for (int mi = 0; mi < 4; ++mi)
#pragma unroll
      for (int ni = 0; ni < 4; ++ni)
        acc[mi][ni] = __builtin_amdgcn_mfma_f32_16x16x32_bf16(
            af[mi], bf[ni], acc[mi][ni], 0, 0, 0);
    __syncthreads();
  }

#pragma unroll
  for (int mi = 0; mi < 4; ++mi)
#pragma unroll
    for (int ni = 0; ni < 4; ++ni)
#pragma unroll
      for (int r = 0; r < 4; ++r) {
        int row = row0 + wrow + mi * 16 + quad * 4 + r;
        int col = col0 + wcol + ni * 16 + l15;
        Cout[nb * obuf_stride + (size_t)row * GN + col] = f2bf(acc[mi][ni][r]);
      }
}

// ---------------------------------------------------------------------------
// Split-K GEMM for the O-projection: C[M,2048] += A[M,K]*B[2048,K]^T over
// K-half blockIdx.z. fp32 atomicAdd epilogue into pre-zeroed d_out.
// ---------------------------------------------------------------------------
__global__ __launch_bounds__(256) void gemm_sk(
    const unsigned short* __restrict__ A, const unsigned short* __restrict__ B,
    float* __restrict__ Cout) {
  __shared__ short As[128 * 32];
  __shared__ short Bs[128 * 32];
  const int t = threadIdx.x;
  const int wave = t >> 6, lane = t & 63;
  const int row0 = blockIdx.x * 128, col0 = blockIdx.y * 128;
  const int k0 = blockIdx.z * 1024;
  const int wrow = (wave >> 1) * 64, wcol = (wave & 1) * 64;

  f32x4 acc[4][4] = {};

  const int srow = wave * 16 + (lane >> 2);
  const int cg = (lane & 3) ^ (lane >> 4);
  const unsigned short* Ag0 = A + (size_t)(row0 + srow) * GK + cg * 8;
  const unsigned short* Ag1 = A + (size_t)(row0 + 64 + srow) * GK + cg * 8;
  const unsigned short* Bg0 = B + (size_t)(col0 + srow) * GK + cg * 8;
  const unsigned short* Bg1 = B + (size_t)(col0 + 64 + srow) * GK + cg * 8;
  char* lA0 = (char*)As + wave * 1024;
  char* lA1 = (char*)As + 4096 + wave * 1024;
  char* lB0 = (char*)Bs + wave * 1024;
  char* lB1 = (char*)Bs + 4096 + wave * 1024;

  const int quad = lane >> 4, l15 = lane & 15;
  const int cpos = quad ^ ((l15 >> 2) & 3);
  const short* ap[4];
  const short* bp[4];
#pragma unroll
  for (int i = 0; i < 4; ++i) {
    ap[i] = As + (wrow + i * 16 + l15) * 32 + cpos * 8;
    bp[i] = Bs + (wcol + i * 16 + l15) * 32 + cpos * 8;
  }

  for (int kk = k0; kk < k0 + 1024; kk += 32) {
    async16(Ag0 + kk, lA0);
    async16(Ag1 + kk, lA1);
    async16(Bg0 + kk, lB0);
    async16(Bg1 + kk, lB1);
    __syncthreads();
    short8 af[4], bf[4];
#pragma unroll
    for (int i = 0; i < 4; ++i) af[i] = *(const short8*)ap[i];
#pragma unroll
    for (int i = 0; i < 4; ++i) bf[i] = *(const short8*)bp[i];
#pragma unroll
    for (int mi = 0; mi < 4; ++mi)
#pragma unroll
      for (int ni = 0; ni < 4; ++ni)
        acc[mi][ni] = __builtin_amdgcn_mfma_f32_16x16x32_bf16(
            af[mi], bf[ni], acc[mi][ni], 0, 0, 0);
    __syncthreads();
  }

#pragma unroll
  for (int mi = 0; mi < 4; ++mi)
#pragma unroll
    for (int ni = 0; ni < 4; ++ni)
#pragma unroll
      for (int r = 0; r < 4; ++r) {
        int row = row0 + wrow + mi * 16 + quad * 4 + r;
        int col = col0 + wcol + ni * 16 + l15;
        atomicAdd(&Cout[(size_t)row * GN + col], acc[mi][ni][r]);
      }
}

// ---------------------------------------------------------------------------
// V transpose: vb[b*S+s][d] -> vtb[(b*H + d>>7)*128 + (d&127)][s]
// ---------------------------------------------------------------------------
__global__ __launch_bounds__(256) void transpose_v(
    const unsigned short* __restrict__ vb, unsigned short* __restrict__ vtb) {
  __shared__ unsigned short tile[64][72];
  const int s0 = blockIdx.x * 64, d0 = blockIdx.y * 64, b = blockIdx.z;
  const int tid = threadIdx.x;
  const int c8 = tid & 7;
#pragma unroll
  for (int i = 0; i < 2; ++i) {
    int row = i * 32 + (tid >> 3);
    uint4 v = *(const uint4*)(vb + (size_t)(b * 2048 + s0 + row) * 2048 + d0 + c8 * 8);
    *(uint4*)&tile[row][c8 * 8] = v;
  }
  __syncthreads();
#pragma unroll
  for (int i = 0; i < 2; ++i) {
    int dr = i * 32 + (tid >> 3);
    short8 sv;
#pragma unroll
    for (int j = 0; j < 8; ++j) sv[j] = (short)tile[c8 * 8 + j][dr];
    int d = d0 + dr;
    int h = d >> 7, hd = d & 127;
    *(short8*)(vtb + ((size_t)(b * 16 + h) * 128 + hd) * 2048 + s0 + c8 * 8) = sv;
  }
}

// ---------------------------------------------------------------------------
// MFMA flash attention, 128 q-rows per block. Block = (q-tile, h, b), 4 waves;
// wave owns 32 q rows (2 m-subtiles). K + V^T staged via global_load_lds
// (swizzled, 2-way free); softmax in C-layout regs; P -> per-wave LDS
// (A-layout, no barrier) -> PV MFMA. Wave-level skip of out-of-window tiles.
// ---------------------------------------------------------------------------
__global__ __launch_bounds__(256, 2) void attn_mfma(
    const unsigned short* __restrict__ Qm, const unsigned short* __restrict__ Km,
    const unsigned short* __restrict__ Vt, unsigned short* __restrict__ Om,
    const int* __restrict__ amask, const int* __restrict__ winp) {
  constexpr int S = 2048, D = 2048, HD = 128;
  const float SCALE = 0.08838834764831845f;  // 1/sqrt(128)

  __shared__ short Ks[64 * 128];       // K[key][d], swizzled 16 chunks/row
  __shared__ short Vts[128 * 64];      // Vt[d][key], swizzled 8 chunks/row
  __shared__ short Ps[4][2][16 * 64];  // per-wave, per-mi P[q][key]

  const int t = threadIdx.x, w = t >> 6, lane = t & 63;
  const int quad = lane >> 4, l15 = lane & 15;
  const int l7 = l15 & 7;
  const int qt = blockIdx.x, h = blockIdx.y, b = blockIdx.z;
  const int qi0 = qt * 128;
  const int win = winp[0];

  short8 qf[2][4];
#pragma unroll
  for (int mi = 0; mi < 2; ++mi) {
    const unsigned short* qp =
        Qm + (size_t)(b * S + qi0 + w * 32 + mi * 16 + l15) * D + h * HD + quad * 8;
#pragma unroll
    for (int kc = 0; kc < 4; ++kc) qf[mi][kc] = *(const short8*)(qp + kc * 32);
  }

  f32x4 o[2][8] = {};
  float m_r[2][4], l_r[2][4];
#pragma unroll
  for (int mi = 0; mi < 2; ++mi)
#pragma unroll
    for (int r = 0; r < 4; ++r) { m_r[mi][r] = -1e30f; l_r[mi][r] = 0.f; }

  int lowj = qi0 - win + 1;
  if (lowj < 0) lowj = 0;
  const int jt0 = lowj >> 6, jt1 = 2 * qt + 1;

  const int gmin = qi0 + w * 32, gmax = gmin + 31;
  const int krow = lane >> 4, kpos = lane & 15;
  const int vrow = lane >> 3, vpos = lane & 7;

  for (int jt = jt0; jt <= jt1; ++jt) {
    const int j0 = jt * 64;
    __syncthreads();  // (A) prev tile's LDS reads done
#pragma unroll
    for (int ii = 0; ii < 4; ++ii) {
      int row = ii * 16 + w * 4 + krow;
      int c = kpos ^ (row & 7);
      async16(Km + (size_t)(b * S + j0 + row) * D + h * HD + c * 8,
              (char*)Ks + (ii * 16 + w * 4) * 256);
    }
#pragma unroll
    for (int ii = 0; ii < 4; ++ii) {
      int row = ii * 32 + w * 8 + vrow;
      int c = vpos ^ (row & 7);
      async16(Vt + ((size_t)(b * 16 + h) * 128 + row) * S + j0 + c * 8,
              (char*)Vts + (ii * 32 + w * 8) * 128);
    }
    __syncthreads();  // (B) K, Vt visible

    if (j0 > gmax || j0 + 63 < gmin - win + 1) continue;

    int amv[4];
#pragma unroll
    for (int ni = 0; ni < 4; ++ni) amv[ni] = amask[b * S + j0 + ni * 16 + l15];

    f32x4 sS[2][4];
#pragma unroll
    for (int ni = 0; ni < 4; ++ni) {
      f32x4 a0 = {0.f, 0.f, 0.f, 0.f}, a1 = {0.f, 0.f, 0.f, 0.f};
#pragma unroll
      for (int kc = 0; kc < 4; ++kc) {
        int pos = (kc * 4 + quad) ^ l7;
        short8 bk = *(const short8*)&Ks[(ni * 16 + l15) * 128 + pos * 8];
        a0 = __builtin_amdgcn_mfma_f32_16x16x32_bf16(qf[0][kc], bk, a0, 0, 0, 0);
        a1 = __builtin_amdgcn_mfma_f32_16x16x32_bf16(qf[1][kc], bk, a1, 0, 0, 0);
      }
      sS[0][ni] = a0;
      sS[1][ni] = a1;
    }

    float alpha[2][4];
#pragma unroll
    for (int mi = 0; mi < 2; ++mi) {
      float sv[4][4];
#pragma unroll
      for (int ni = 0; ni < 4; ++ni)
#pragma unroll
        for (int r = 0; r < 4; ++r) {
          int gi = qi0 + w * 32 + mi * 16 + quad * 4 + r;
          int gj = j0 + ni * 16 + l15;
          bool ok = (gj <= gi) && (gj >= gi - win + 1) && (amv[ni] != 0);
          sv[ni][r] = ok ? sS[mi][ni][r] * SCALE : -1e30f;
        }
      float mnew[4];
#pragma unroll
      for (int r = 0; r < 4; ++r) {
        float mx = fmaxf(fmaxf(sv[0][r], sv[1][r]), fmaxf(sv[2][r], sv[3][r]));
        mx = fmaxf(mx, __shfl_xor(mx, 1));
        mx = fmaxf(mx, __shfl_xor(mx, 2));
        mx = fmaxf(mx, __shfl_xor(mx, 4));
        mx = fmaxf(mx, __shfl_xor(mx, 8));
        float mn = fmaxf(m_r[mi][r], mx);
        alpha[mi][r] = __expf(m_r[mi][r] - mn);
        m_r[mi][r] = mn;
        mnew[r] = mn;
      }
      float rs[4] = {0.f, 0.f, 0.f, 0.f};
#pragma unroll
      for (int ni = 0; ni < 4; ++ni)
#pragma unroll
        for (int r = 0; r < 4; ++r) {
          float p = (sv[ni][r] > -1e29f) ? __expf(sv[ni][r] - mnew[r]) : 0.f;
          sv[ni][r] = p;
          rs[r] += p;
        }
#pragma unroll
      for (int r = 0; r < 4; ++r) {
        float s = rs[r];
        s += __shfl_xor(s, 1);
        s += __shfl_xor(s, 2);
        s += __shfl_xor(s, 4);
        s += __shfl_xor(s, 8);
        l_r[mi][r] = l_r[mi][r] * alpha[mi][r] + s;
      }
#pragma unroll
      for (int ni = 0; ni < 4; ++ni)
#pragma unroll
        for (int r = 0; r < 4; ++r) {
          int row = quad * 4 + r;
          int col = ni * 16 + l15;
          int pos = (col >> 3) ^ (row & 7);
          Ps[w][mi][row * 64 + pos * 8 + (col & 7)] = (short)f2bf(sv[ni][r]);
        }
    }
#pragma unroll
    for (int mi = 0; mi < 2; ++mi)
#pragma unroll
      for (int ni2 = 0; ni2 < 8; ++ni2)
#pragma unroll
        for (int r = 0; r < 4; ++r) o[mi][ni2][r] *= alpha[mi][r];

    __asm__ __volatile__("s_waitcnt lgkmcnt(0)" ::: "memory");

    short8 aP[2][2];
#pragma unroll
    for (int mi = 0; mi < 2; ++mi)
#pragma unroll
      for (int kc2 = 0; kc2 < 2; ++kc2) {
        int pos = (kc2 * 4 + quad) ^ l7;
        aP[mi][kc2] = *(const short8*)&Ps[w][mi][l15 * 64 + pos * 8];
      }
#pragma unroll
    for (int ni2 = 0; ni2 < 8; ++ni2)
#pragma unroll
      for (int kc2 = 0; kc2 < 2; ++kc2) {
        int pos = (kc2 * 4 + quad) ^ l7;
        short8 bv = *(const short8*)&Vts[(ni2 * 16 + l15) * 64 + pos * 8];
        o[0][ni2] = __builtin_amdgcn_mfma_f32_16x16x32_bf16(aP[0][kc2], bv,
                                                            o[0][ni2], 0, 0, 0);
        o[1][ni2] = __builtin_amdgcn_mfma_f32_16x16x32_bf16(aP[1][kc2], bv,
                                                            o[1][ni2], 0, 0, 0);
      }
  }

#pragma unroll
  for (int mi = 0; mi < 2; ++mi) {
    float inv[4];
#pragma unroll
    for (int r = 0; r < 4; ++r) inv[r] = 1.f / l_r[mi][r];
#pragma unroll
    for (int ni2 = 0; ni2 < 8; ++ni2)
#pragma unroll
      for (int r = 0; r < 4; ++r) {
        int row = qi0 + w * 32 + mi * 16 + quad * 4 + r;
        Om[(size_t)(b * S + row) * D + h * HD + ni2 * 16 + l15] =
            f2bf(o[mi][ni2][r] * inv[r]);
      }
  }
}

// ---------------------------------------------------------------------------
extern "C" void kernel_launch(void* const* d_in, const int* in_sizes, int n_in,
                              void* d_out, int out_size, void* d_ws,
                              size_t ws_size, hipStream_t stream) {
  (void)in_sizes; (void)n_in; (void)out_size; (void)ws_size;
  const float* x  = (const float*)d_in[0];
  const float* Wq = (const float*)d_in[1];
  const float* Wk = (const float*)d_in[2];
  const float* Wv = (const float*)d_in[3];
  const float* Wo = (const float*)d_in[4];
  const int* am   = (const int*)d_in[5];
  const int* win  = (const int*)d_in[6];
  // d_in[7] sink_tokens: unused (sink mask == causal per reference)

  char* ws = (char*)d_ws;  // needs >= 112 MB
  unsigned short* xb   = (unsigned short*)(ws + 0);
  unsigned short* vtb  = (unsigned short*)(ws + 0);  // aliases xb (dead then)
  unsigned short* wqkv = (unsigned short*)(ws + 16777216);  // [6144,2048]
  unsigned short* wob  = (unsigned short*)(ws + 41943040);
  unsigned short* qb   = (unsigned short*)(ws + 50331648);
  unsigned short* vb   = (unsigned short*)(ws + 83886080);  // qb + 2*8388608
  unsigned short* ab   = (unsigned short*)(ws + 100663296);

  // zero d_out for the split-K atomic epilogue (memset node: graph-safe)
  hipMemsetAsync(d_out, 0, (size_t)out_size * sizeof(float), stream);

  cast_all<<<dim3(12288), dim3(256), 0, stream>>>(x, Wq, Wk, Wv, Wo, xb, wqkv, wob);

  // fused QKV: N_total = 6144; col block >>11 -> {qb, kb, vb}
  gemm_bt<<<dim3(32, 48), dim3(256), 0, stream>>>(xb, wqkv, qb, 8388608);

  transpose_v<<<dim3(32, 32, 2), dim3(256), 0, stream>>>(vb, vtb);

  attn_mfma<<<dim3(16, 16, 2), dim3(256), 0, stream>>>(qb, qb + 8388608, vtb,
                                                       ab, am, win);

  // O-projection: split-K=2, fp32 atomic accumulate into d_out
  gemm_sk<<<dim3(32, 16, 2), dim3(256), 0, stream>>>(ab, wob, (float*)d_out);
}

// Round 5
// 371.595 us; speedup vs baseline: 1.1273x; 1.1273x over previous
//
#include <hip/hip_runtime.h>
#include <stdint.h>

// ============================================================================
// R5: revert R4's atomics + revert attn to the measured-68µs R2 structure
//     (64 q-rows/block, grid 1024) with an XCD-aware block swizzle for K/V
//     L2 locality. Fused cast kept. Plain Wo GEMM (fp32 store) kept.
// Shapes fixed: B=2, S=2048, D=2048, H=16, HD=128, window=512 (runtime-read).
// ws layout (bytes): xb@0 (16M, vtb aliases after QKV gemm) | wqkv@16M (25.2M)
//   wob@41.9M | qb@48M kb@64M vb@80M (16M apart = 8388608 elems) | ab@96M.
// ============================================================================

typedef __attribute__((ext_vector_type(8))) short short8;
typedef __attribute__((ext_vector_type(4))) float f32x4;

#define DEV static __device__ __forceinline__

DEV unsigned short f2bf(float f) {
  unsigned u = __builtin_bit_cast(unsigned, f);
  u += 0x7fffu + ((u >> 16) & 1u);  // RNE
  return (unsigned short)(u >> 16);
}

// async global->LDS, 16B/lane; LDS dest = wave-uniform base + lane*16
DEV void async16(const void* g, void* l) {
  __builtin_amdgcn_global_load_lds(
      (const __attribute__((address_space(1))) unsigned int*)g,
      (__attribute__((address_space(3))) unsigned int*)l, 16, 0, 0);
}

// ---------------------------------------------------------------------------
// Fused fp32 -> bf16 cast for x + Wq + Wk + Wv + Wo. 8 elems/thread.
// ---------------------------------------------------------------------------
__global__ __launch_bounds__(256) void cast_all(
    const float* __restrict__ x, const float* __restrict__ Wq,
    const float* __restrict__ Wk, const float* __restrict__ Wv,
    const float* __restrict__ Wo, unsigned short* __restrict__ xb,
    unsigned short* __restrict__ wqkv, unsigned short* __restrict__ wob) {
  const int bid = blockIdx.x;
  const float* src;
  unsigned short* dst;
  int i;
  if (bid < 4096) {
    src = x; dst = xb; i = bid * 256 + threadIdx.x;
  } else if (bid < 6144) {
    src = Wq; dst = wqkv; i = (bid - 4096) * 256 + threadIdx.x;
  } else if (bid < 8192) {
    src = Wk; dst = wqkv + 4194304; i = (bid - 6144) * 256 + threadIdx.x;
  } else if (bid < 10240) {
    src = Wv; dst = wqkv + 8388608; i = (bid - 8192) * 256 + threadIdx.x;
  } else {
    src = Wo; dst = wob; i = (bid - 10240) * 256 + threadIdx.x;
  }
  const float4* s4 = (const float4*)src;
  float4 a = s4[2 * (size_t)i], b = s4[2 * (size_t)i + 1];
  short8 o;
  o[0] = (short)f2bf(a.x); o[1] = (short)f2bf(a.y);
  o[2] = (short)f2bf(a.z); o[3] = (short)f2bf(a.w);
  o[4] = (short)f2bf(b.x); o[5] = (short)f2bf(b.y);
  o[6] = (short)f2bf(b.z); o[7] = (short)f2bf(b.w);
  *(short8*)(dst + 8 * (size_t)i) = o;
}

// ---------------------------------------------------------------------------
// C = A[M,K] * B[NT,K]^T, k-contiguous bf16. M=4096, K=2048.
// grid.y*128 = global col; nb = col>>11 selects output buffer (stride
// obuf_stride elems); local col = col & 2047, row stride 2048.
// ---------------------------------------------------------------------------
constexpr int GK = 2048, GN = 2048;

template <bool STORE_BF16>
__global__ __launch_bounds__(256) void gemm_bt(
    const unsigned short* __restrict__ A, const unsigned short* __restrict__ B,
    void* __restrict__ Cout, size_t obuf_stride) {
  __shared__ short As[128 * 32];
  __shared__ short Bs[128 * 32];
  const int t = threadIdx.x;
  const int wave = t >> 6, lane = t & 63;
  const int row0 = blockIdx.x * 128;
  const int col0g = blockIdx.y * 128;            // global col in [0, N_total)
  const int nb = col0g >> 11, col0 = col0g & 2047;
  const int wrow = (wave >> 1) * 64, wcol = (wave & 1) * 64;

  f32x4 acc[4][4] = {};

  const int srow = wave * 16 + (lane >> 2);
  const int cg = (lane & 3) ^ (lane >> 4);
  const unsigned short* Ag0 = A + (size_t)(row0 + srow) * GK + cg * 8;
  const unsigned short* Ag1 = A + (size_t)(row0 + 64 + srow) * GK + cg * 8;
  const unsigned short* Bg0 = B + (size_t)(col0g + srow) * GK + cg * 8;
  const unsigned short* Bg1 = B + (size_t)(col0g + 64 + srow) * GK + cg * 8;
  char* lA0 = (char*)As + wave * 1024;
  char* lA1 = (char*)As + 4096 + wave * 1024;
  char* lB0 = (char*)Bs + wave * 1024;
  char* lB1 = (char*)Bs + 4096 + wave * 1024;

  const int quad = lane >> 4, l15 = lane & 15;
  const int cpos = quad ^ ((l15 >> 2) & 3);
  const short* ap[4];
  const short* bp[4];
#pragma unroll
  for (int i = 0; i < 4; ++i) {
    ap[i] = As + (wrow + i * 16 + l15) * 32 + cpos * 8;
    bp[i] = Bs + (wcol + i * 16 + l15) * 32 + cpos * 8;
  }

  for (int kk = 0; kk < GK; kk += 32) {
    async16(Ag0 + kk, lA0);
    async16(Ag1 + kk, lA1);
    async16(Bg0 + kk, lB0);
    async16(Bg1 + kk, lB1);
    __syncthreads();
    short8 af[4], bf[4];
#pragma unroll
    for (int i = 0; i < 4; ++i) af[i] = *(const short8*)ap[i];
#pragma unroll
    for (int i = 0; i < 4; ++i) bf[i] = *(const short8*)bp[i];
#pragma unroll
    for (int mi = 0; mi < 4; ++mi)
#pragma unroll
      for (int ni = 0; ni < 4; ++ni)
        acc[mi][ni] = __builtin_amdgcn_mfma_f32_16x16x32_bf16(
            af[mi], bf[ni], acc[mi][ni], 0, 0, 0);
    __syncthreads();
  }

#pragma unroll
  for (int mi = 0; mi < 4; ++mi)
#pragma unroll
    for (int ni = 0; ni < 4; ++ni)
#pragma unroll
      for (int r = 0; r < 4; ++r) {
        int row = row0 + wrow + mi * 16 + quad * 4 + r;
        int col = col0 + wcol + ni * 16 + l15;
        if (STORE_BF16)
          ((unsigned short*)Cout)[nb * obuf_stride + (size_t)row * GN + col] =
              f2bf(acc[mi][ni][r]);
        else
          ((float*)Cout)[nb * obuf_stride + (size_t)row * GN + col] =
              acc[mi][ni][r];
      }
}

// ---------------------------------------------------------------------------
// V transpose: vb[b*S+s][d] -> vtb[(b*H + d>>7)*128 + (d&127)][s]
// ---------------------------------------------------------------------------
__global__ __launch_bounds__(256) void transpose_v(
    const unsigned short* __restrict__ vb, unsigned short* __restrict__ vtb) {
  __shared__ unsigned short tile[64][72];
  const int s0 = blockIdx.x * 64, d0 = blockIdx.y * 64, b = blockIdx.z;
  const int tid = threadIdx.x;
  const int c8 = tid & 7;
#pragma unroll
  for (int i = 0; i < 2; ++i) {
    int row = i * 32 + (tid >> 3);
    uint4 v = *(const uint4*)(vb + (size_t)(b * 2048 + s0 + row) * 2048 + d0 + c8 * 8);
    *(uint4*)&tile[row][c8 * 8] = v;
  }
  __syncthreads();
#pragma unroll
  for (int i = 0; i < 2; ++i) {
    int dr = i * 32 + (tid >> 3);
    short8 sv;
#pragma unroll
    for (int j = 0; j < 8; ++j) sv[j] = (short)tile[c8 * 8 + j][dr];
    int d = d0 + dr;
    int h = d >> 7, hd = d & 127;
    *(short8*)(vtb + ((size_t)(b * 16 + h) * 128 + hd) * 2048 + s0 + c8 * 8) = sv;
  }
}

// ---------------------------------------------------------------------------
// MFMA flash attention (R2 structure, measured 68 µs). Block = 64 q-rows of
// one (b,h); 4 waves, wave owns 16 q rows. Grid is FLAT 1024 with XCD-aware
// mapping: f = qt*32 + g (g = b*16+h), so all 32 q-tiles of a (b,h) group
// land on XCD g%8 (4 groups/XCD -> ~4MB K+V resident per XCD L2).
// ---------------------------------------------------------------------------
__global__ __launch_bounds__(256, 3) void attn_mfma(
    const unsigned short* __restrict__ Qm, const unsigned short* __restrict__ Km,
    const unsigned short* __restrict__ Vt, unsigned short* __restrict__ Om,
    const int* __restrict__ amask, const int* __restrict__ winp) {
  constexpr int S = 2048, D = 2048, HD = 128;
  const float SCALE = 0.08838834764831845f;  // 1/sqrt(128)

  __shared__ short Ks[64 * 128];   // K[key][d], chunk-swizzled (16 chunks/row)
  __shared__ short Vts[128 * 64];  // Vt[d][key], chunk-swizzled (8 chunks/row)
  __shared__ short Ps[4][16 * 64]; // per-wave P[q][key], swizzled (8 chunks/row)

  const int t = threadIdx.x, w = t >> 6, lane = t & 63;
  const int quad = lane >> 4, l15 = lane & 15;
  const int l7 = l15 & 7;
  // XCD-aware decode: f = qt*32 + (b*16+h)
  const int f = blockIdx.x;
  const int qt = f >> 5, g = f & 31;
  const int h = g & 15, b = g >> 4;
  const int qi0 = qt * 64;
  const int win = winp[0];

  // Q A-frags: A[m=l15][k=quad*8+j], 4 k-chunks of 32
  short8 qf[4];
  {
    const unsigned short* qp =
        Qm + (size_t)(b * S + qi0 + w * 16 + l15) * D + h * HD + quad * 8;
#pragma unroll
    for (int kc = 0; kc < 4; ++kc) qf[kc] = *(const short8*)(qp + kc * 32);
  }

  f32x4 o[8] = {};              // O[q=quad*4+r][d=ni2*16+l15]
  float m_r[4], l_r[4];
#pragma unroll
  for (int r = 0; r < 4; ++r) { m_r[r] = -1e30f; l_r[r] = 0.f; }

  int lowj = qi0 - win + 1;
  if (lowj < 0) lowj = 0;
  const int jt0 = lowj >> 6;

  const int krow = lane >> 4, kpos = lane & 15;  // K staging
  const int vrow = lane >> 3, vpos = lane & 7;   // Vt staging

  for (int jt = jt0; jt <= qt; ++jt) {
    const int j0 = jt * 64;
    __syncthreads();  // (A) prev tile's LDS reads done
#pragma unroll
    for (int ii = 0; ii < 4; ++ii) {
      int row = ii * 16 + w * 4 + krow;
      int c = kpos ^ (row & 7);
      async16(Km + (size_t)(b * S + j0 + row) * D + h * HD + c * 8,
              (char*)Ks + (ii * 16 + w * 4) * 256);
    }
#pragma unroll
    for (int ii = 0; ii < 4; ++ii) {
      int row = ii * 32 + w * 8 + vrow;
      int c = vpos ^ (row & 7);
      async16(Vt + ((size_t)(b * 16 + h) * 128 + row) * S + j0 + c * 8,
              (char*)Vts + (ii * 32 + w * 8) * 128);
    }
    __syncthreads();  // (B) K, Vt visible

    // ---- QK^T: S[q=quad*4+r][key=ni*16+l15] ----
    f32x4 sS[4];
#pragma unroll
    for (int ni = 0; ni < 4; ++ni) {
      f32x4 acc = {0.f, 0.f, 0.f, 0.f};
#pragma unroll
      for (int kc = 0; kc < 4; ++kc) {
        int pos = (kc * 4 + quad) ^ l7;
        short8 bk = *(const short8*)&Ks[(ni * 16 + l15) * 128 + pos * 8];
        acc = __builtin_amdgcn_mfma_f32_16x16x32_bf16(qf[kc], bk, acc, 0, 0, 0);
      }
      sS[ni] = acc;
    }

    // ---- mask + online softmax (quad-local rows) ----
    float sv[4][4];
    int amv[4];
#pragma unroll
    for (int ni = 0; ni < 4; ++ni) amv[ni] = amask[b * S + j0 + ni * 16 + l15];
#pragma unroll
    for (int ni = 0; ni < 4; ++ni)
#pragma unroll
      for (int r = 0; r < 4; ++r) {
        int gi = qi0 + w * 16 + quad * 4 + r;
        int gj = j0 + ni * 16 + l15;
        bool ok = (gj <= gi) && (gj >= gi - win + 1) && (amv[ni] != 0);
        sv[ni][r] = ok ? sS[ni][r] * SCALE : -1e30f;
      }
    float alpha[4], mnew[4];
#pragma unroll
    for (int r = 0; r < 4; ++r) {
      float mx = fmaxf(fmaxf(sv[0][r], sv[1][r]), fmaxf(sv[2][r], sv[3][r]));
      mx = fmaxf(mx, __shfl_xor(mx, 1));
      mx = fmaxf(mx, __shfl_xor(mx, 2));
      mx = fmaxf(mx, __shfl_xor(mx, 4));
      mx = fmaxf(mx, __shfl_xor(mx, 8));
      float mn = fmaxf(m_r[r], mx);
      alpha[r] = __expf(m_r[r] - mn);
      m_r[r] = mn;
      mnew[r] = mn;
    }
    float rs[4] = {0.f, 0.f, 0.f, 0.f};
#pragma unroll
    for (int ni = 0; ni < 4; ++ni)
#pragma unroll
      for (int r = 0; r < 4; ++r) {
        float p = (sv[ni][r] > -1e29f) ? __expf(sv[ni][r] - mnew[r]) : 0.f;
        sv[ni][r] = p;
        rs[r] += p;
      }
#pragma unroll
    for (int r = 0; r < 4; ++r) {
      float s = rs[r];
      s += __shfl_xor(s, 1);
      s += __shfl_xor(s, 2);
      s += __shfl_xor(s, 4);
      s += __shfl_xor(s, 8);
      l_r[r] = l_r[r] * alpha[r] + s;
    }
    // write P (bf16) into this wave's A-layout tile
#pragma unroll
    for (int ni = 0; ni < 4; ++ni)
#pragma unroll
      for (int r = 0; r < 4; ++r) {
        int row = quad * 4 + r;
        int col = ni * 16 + l15;
        int pos = (col >> 3) ^ (row & 7);
        Ps[w][row * 64 + pos * 8 + (col & 7)] = (short)f2bf(sv[ni][r]);
      }
    // rescale O
#pragma unroll
    for (int ni2 = 0; ni2 < 8; ++ni2)
#pragma unroll
      for (int r = 0; r < 4; ++r) o[ni2][r] *= alpha[r];

    // same-wave LDS write->read: drain lgkm, no barrier needed
    __asm__ __volatile__("s_waitcnt lgkmcnt(0)" ::: "memory");

    // ---- PV: O[q][d] += P[q][key] * Vt[d][key]^T ----
    short8 aP[2];
#pragma unroll
    for (int kc2 = 0; kc2 < 2; ++kc2) {
      int pos = (kc2 * 4 + quad) ^ l7;
      aP[kc2] = *(const short8*)&Ps[w][l15 * 64 + pos * 8];
    }
#pragma unroll
    for (int ni2 = 0; ni2 < 8; ++ni2) {
#pragma unroll
      for (int kc2 = 0; kc2 < 2; ++kc2) {
        int pos = (kc2 * 4 + quad) ^ l7;
        short8 bv = *(const short8*)&Vts[(ni2 * 16 + l15) * 64 + pos * 8];
        o[ni2] = __builtin_amdgcn_mfma_f32_16x16x32_bf16(aP[kc2], bv, o[ni2], 0, 0, 0);
      }
    }
  }

  // epilogue: O / l
  float inv[4];
#pragma unroll
  for (int r = 0; r < 4; ++r) inv[r] = 1.f / l_r[r];
#pragma unroll
  for (int ni2 = 0; ni2 < 8; ++ni2)
#pragma unroll
    for (int r = 0; r < 4; ++r) {
      int row = qi0 + w * 16 + quad * 4 + r;
      Om[(size_t)(b * S + row) * D + h * HD + ni2 * 16 + l15] =
          f2bf(o[ni2][r] * inv[r]);
    }
}

// ---------------------------------------------------------------------------
extern "C" void kernel_launch(void* const* d_in, const int* in_sizes, int n_in,
                              void* d_out, int out_size, void* d_ws,
                              size_t ws_size, hipStream_t stream) {
  (void)in_sizes; (void)n_in; (void)out_size; (void)ws_size;
  const float* x  = (const float*)d_in[0];
  const float* Wq = (const float*)d_in[1];
  const float* Wk = (const float*)d_in[2];
  const float* Wv = (const float*)d_in[3];
  const float* Wo = (const float*)d_in[4];
  const int* am   = (const int*)d_in[5];
  const int* win  = (const int*)d_in[6];
  // d_in[7] sink_tokens: unused (sink mask == causal per reference)

  char* ws = (char*)d_ws;  // needs >= 112 MB
  unsigned short* xb   = (unsigned short*)(ws + 0);
  unsigned short* vtb  = (unsigned short*)(ws + 0);  // aliases xb (dead then)
  unsigned short* wqkv = (unsigned short*)(ws + 16777216);  // [6144,2048]
  unsigned short* wob  = (unsigned short*)(ws + 41943040);
  unsigned short* qb   = (unsigned short*)(ws + 50331648);
  unsigned short* kb   = (unsigned short*)(ws + 67108864);  // qb + 8388608
  unsigned short* vb   = (unsigned short*)(ws + 83886080);  // qb + 2*8388608
  unsigned short* ab   = (unsigned short*)(ws + 100663296);

  cast_all<<<dim3(12288), dim3(256), 0, stream>>>(x, Wq, Wk, Wv, Wo, xb, wqkv, wob);

  // fused QKV: N_total = 6144; col block >>11 -> {qb, kb, vb}
  gemm_bt<true><<<dim3(32, 48), dim3(256), 0, stream>>>(xb, wqkv, qb, 8388608);

  transpose_v<<<dim3(32, 32, 2), dim3(256), 0, stream>>>(vb, vtb);

  // flat 1024-block grid, XCD-swizzled (f = qt*32 + b*16 + h)
  attn_mfma<<<dim3(1024), dim3(256), 0, stream>>>(qb, kb, vtb, ab, am, win);

  gemm_bt<false><<<dim3(32, 16), dim3(256), 0, stream>>>(ab, wob, d_out, 0);
}